// Round 10
// baseline (45.320 us; speedup 1.0000x reference)
//
#include <hip/hip_runtime.h>
#include <math.h>

namespace {
constexpr int kNB  = 16;
constexpr int kNF  = 512;
constexpr int kNTS = 2048;
constexpr int kTPB = 256;                // 4 waves per block
constexpr int kBinsPerBlock = 2;         // 2 bins/block -> 128 threads per bin
constexpr int kTPG = kTPB / kBinsPerBlock;   // 128 threads per group(bin)
constexpr int kEPT = kNTS / kTPG;        // 16 elements per thread
constexpr int kVPT = kEPT / 4;           // 4 float4 loads per array
// 1/(8*pi^2) rounded to fp32
constexpr float kC     = 0.012665147955292222f;
// kC * log2(e): folds __expf's log2e pre-multiply into the Gaussian constant.
// w deviation vs ref's expf path ~1-2 ulp of the exp2 argument (coherent across
// both passes) -- same noise class as the poly-sincos swap that passed R2-R9.
constexpr float kCL2   = 0.0182719460f;
constexpr float kTwoPi = 6.28318530717958647692f;

constexpr float kTwoOverPi = 0.636619772367581343f;
constexpr float kP1 = 1.5703125f;               // 201 * 2^-7
constexpr float kP2 = 4.84466552734375e-4f;     // 127 * 2^-18
constexpr float kP3 = -6.407499313354492e-7f;   // -86 * 2^-27
constexpr float kP4 = 9.895302355289459e-10f;   //  68 * 2^-36
}

// Branchless sincos for |x| < 2^17 (args bounded by ~1.3e5).
// fp32 Cody-Waite mod pi/2 (7-bit chunks, k*ci exact for k<2^17) + Cephes
// minimax polys. Error ~4e-7 abs. (Razor-validated: this per-element accuracy
// class passes; ~2e-6-class shortcuts flip the phase branch cut — rounds 6/7.)
__device__ __forceinline__ void fast_sincosf(float x, float& s_out, float& c_out) {
  float kf = rintf(x * kTwoOverPi);
  int   q  = (int)kf;
  float r  = fmaf(-kf, kP1, x);
  r = fmaf(-kf, kP2, r);
  r = fmaf(-kf, kP3, r);
  r = fmaf(-kf, kP4, r);

  float z = r * r;
  float sp = fmaf(fmaf(-1.9515295891e-4f, z, 8.3321608736e-3f), z, -1.6666654611e-1f);
  float s  = fmaf(sp * z, r, r);
  float cp = fmaf(fmaf(2.443315711809948e-5f, z, -1.388731625493765e-3f), z,
                  4.166664568298827e-2f);
  float c  = fmaf(cp, z * z, fmaf(-0.5f, z, 1.0f));

  bool sw = (q & 1) != 0;
  float ss = sw ? c : s;
  float cc = sw ? s : c;
  unsigned sgn_s = (unsigned)(q & 2) << 30;
  unsigned sgn_c = (unsigned)((q + 1) & 2) << 30;
  s_out = __uint_as_float(__float_as_uint(ss) ^ sgn_s);
  c_out = __uint_as_float(__float_as_uint(cc) ^ sgn_c);
}

// 2 bins per 4-wave block: keeps the proven round-3/9 block shape (4 waves,
// barriers, ~51% occ) while doubling EPT to 16 -> butterfly amortization
// halves (10 accs x 6 stages x 2 instrs over 16 elems instead of 8).
// Bins (2f', 2f'+1) share b (NF even), so ts/ys rows are L1-shared.
__launch_bounds__(kTPB, 4)
__global__ void wavelet_ls_kernel(const float* __restrict__ ys,
                                  const float* __restrict__ ts,
                                  const float* __restrict__ freq,
                                  float* __restrict__ out) {
  const int tid   = threadIdx.x;
  const int group = tid >> 7;            // 0/1: which bin of this block
  const int gtid  = tid & (kTPG - 1);    // 0..127 within group
  const int gwave = (tid >> 6) & 1;      // 0/1: wave within group
  const int bin   = blockIdx.x * kBinsPerBlock + group;
  const int b     = bin >> 9;            // kNF = 512
  const int f     = bin & (kNF - 1);

  const float* __restrict__ tsb = ts + b * kNTS;
  const float* __restrict__ ysb = ys + b * kNTS;
  const float4* __restrict__ ts4 = (const float4*)tsb;
  const float4* __restrict__ ys4 = (const float4*)ysb;

  const float tau   = 0.5f * (tsb[kNTS / 2] + tsb[kNTS / 2 + 1]);
  const float omega = freq[f] * kTwoPi;

  // Per-thread sample state kept across both passes.
  float tv[kEPT], wv[kEPT], wyv[kEPT];

  // Pass-1 accumulators (6): sum_w, w*sin, w*cos, w*(sin*cos), w*(cos^2-sin^2), w*y
  float acc[6];
#pragma unroll
  for (int i = 0; i < 6; ++i) acc[i] = 0.0f;

#pragma unroll
  for (int v = 0; v < kVPT; ++v) {
    const int vidx = v * kTPG + gtid;     // coalesced float4 within the bin row
    const float4 t4 = ts4[vidx];
    const float4 y4 = ys4[vidx];
    const float te[4] = {t4.x, t4.y, t4.z, t4.w};
    const float ye[4] = {y4.x, y4.y, y4.z, y4.w};
#pragma unroll
    for (int j = 0; j < 4; ++j) {
      const int k = v * 4 + j;
      const float t = te[j];
      const float y = ye[j];
      tv[k] = t;
      const float dz = omega * (t - tau);      // ref rounding structure
      const float e2 = (-kCL2 * dz) * dz;      // exp2-domain exponent
      const float w  = __builtin_amdgcn_exp2f(e2);
      wv[k]  = w;
      wyv[k] = w * y;
      float sn, cs;
      fast_sincosf(omega * t, sn, cs);         // theta = fl(omega*t)
      const float c2 = fmaf(-2.0f * sn, sn, 1.0f);   // cos^2 - sin^2
      acc[0] += w;
      acc[1] = fmaf(w, sn, acc[1]);
      acc[2] = fmaf(w, cs, acc[2]);
      acc[3] = fmaf(w, sn * cs, acc[3]);
      acc[4] = fmaf(w, c2, acc[4]);
      acc[5] = fmaf(w, y, acc[5]);
    }
  }

  // Butterfly within wave; combine the group's 2 waves via LDS.
  __shared__ float lds1[kBinsPerBlock][2][6];
#pragma unroll
  for (int i = 0; i < 6; ++i) {
    float v = acc[i];
#pragma unroll
    for (int off = 1; off < 64; off <<= 1) v += __shfl_xor(v, off, 64);
    if ((tid & 63) == 0) lds1[group][gwave][i] = v;
  }
  __syncthreads();

  float tot[6];
#pragma unroll
  for (int i = 0; i < 6; ++i)
    tot[i] = lds1[group][0][i] + lds1[group][1][i];

  const float sum_w   = tot[0];
  const float inv_w   = 1.0f / sum_w;
  const float sin_one = tot[1] * inv_w;
  const float cos_one = tot[2] * inv_w;
  const float sin_cos = tot[3] * inv_w;
  const float cc_ss   = tot[4] * inv_w;    // cos_cos - sin_sin
  const float ys_one  = tot[5] * inv_w;

  const float num = 2.0f * (sin_cos - sin_one * cos_one);
  const float den = cc_ss - cos_one * cos_one + sin_one * sin_one;
  const float time_shift = atan2f(num, den) / (2.0f * omega);

  // Pass 2: full per-element recompute of sincos(omega*(t - time_shift)).
  // (Rounds 6/7 proved any cheaper path perturbs a2 by ~1e-5 at razor bins
  //  and flips atan2 by 2*pi.)
  float a20 = 0.0f, a21 = 0.0f, a22 = 0.0f, a23 = 0.0f;
#pragma unroll
  for (int k = 0; k < kEPT; ++k) {
    float sn, cs;
    fast_sincosf(omega * (tv[k] - time_shift), sn, cs);   // ref's phase_arg
    const float w  = wv[k];
    const float wy = wyv[k];
    a20 = fmaf(w,  cs, a20);    // -> cos_shift_one
    a21 = fmaf(w,  sn, a21);    // -> sin_shift_one
    a22 = fmaf(wy, cs, a22);    // -> ys_cos_shift
    a23 = fmaf(wy, sn, a23);    // -> ys_sin_shift
  }

  __shared__ float lds2[kBinsPerBlock][2][4];
  {
    float av[4] = {a20, a21, a22, a23};
#pragma unroll
    for (int i = 0; i < 4; ++i) {
      float v = av[i];
#pragma unroll
      for (int off = 1; off < 64; off <<= 1) v += __shfl_xor(v, off, 64);
      if ((tid & 63) == 0) lds2[group][gwave][i] = v;
    }
  }
  __syncthreads();

  if (gtid == 0) {
    float t2[4];
#pragma unroll
    for (int i = 0; i < 4; ++i)
      t2[i] = lds2[group][0][i] + lds2[group][1][i];

    const float cos_shift_one = t2[0] * inv_w;
    const float sin_shift_one = t2[1] * inv_w;
    const float ys_cos_shift  = t2[2] * inv_w;
    const float ys_sin_shift  = t2[3] * inv_w;

    float stc, ctc;
    sincosf(omega * (time_shift - tau), &stc, &ctc);  // once per bin: keep libm

    const float A  = 2.0f * (ys_cos_shift - ys_one * cos_shift_one);
    const float B  = 2.0f * (ys_sin_shift - ys_one * sin_shift_one);
    const float a0 = ys_one;
    const float a1 = ctc * A - stc * B;
    const float a2 = stc * A + ctc * B;
    const float wwp   = a1 * a1 + a2 * a2;
    const float phase = atan2f(a2, a1);

    const int o = b * kNF + f;
    out[0 * kNB * kNF + o] = wwp;
    out[1 * kNB * kNF + o] = phase;
    out[2 * kNB * kNF + o] = a0;
    out[3 * kNB * kNF + o] = a1;
    out[4 * kNB * kNF + o] = a2;
  }
}

extern "C" void kernel_launch(void* const* d_in, const int* in_sizes, int n_in,
                              void* d_out, int out_size, void* d_ws, size_t ws_size,
                              hipStream_t stream) {
  const float* ys   = (const float*)d_in[0];
  const float* ts   = (const float*)d_in[1];
  const float* freq = (const float*)d_in[2];
  float* out = (float*)d_out;

  dim3 grid(kNB * kNF / kBinsPerBlock);   // 4096 blocks x 4 waves
  wavelet_ls_kernel<<<grid, kTPB, 0, stream>>>(ys, ts, freq, out);
}

// Round 11
// 39.258 us; speedup vs baseline: 1.1544x; 1.1544x over previous
//
#include <hip/hip_runtime.h>
#include <math.h>

namespace {
constexpr int kNB  = 16;
constexpr int kNF  = 512;
constexpr int kNTS = 2048;
constexpr int kTPB = 256;
constexpr int kEPT = kNTS / kTPB;   // 8 elements per thread
constexpr int kVPT = kEPT / 4;      // 2 float4 loads per array
// 1/(8*pi^2) rounded to fp32
constexpr float kC     = 0.012665147955292222f;
// kC * log2(e): folds __expf's log2e pre-multiply into the Gaussian constant.
// Razor-validated in round 10 (absmax floor intact).
constexpr float kCL2   = 0.0182719460f;
constexpr float kTwoPi = 6.28318530717958647692f;

constexpr float kTwoOverPi = 0.636619772367581343f;
constexpr float kP1 = 1.5703125f;               // 201 * 2^-7
constexpr float kP2 = 4.84466552734375e-4f;     // 127 * 2^-18
constexpr float kP3 = -6.407499313354492e-7f;   // -86 * 2^-27
constexpr float kP4 = 9.895302355289459e-10f;   //  68 * 2^-36
}

// Branchless sincos for |x| < 2^17 (args bounded by ~1.3e5).
// fp32 Cody-Waite mod pi/2 (7-bit chunks, k*ci exact for k<2^17) + Cephes
// minimax polys. Error ~4e-7 abs. (Razor-validated accuracy class: this passes;
// ~2e-6-class shortcuts flip the phase branch cut — rounds 6/7.)
__device__ __forceinline__ void fast_sincosf(float x, float& s_out, float& c_out) {
  float kf = rintf(x * kTwoOverPi);
  int   q  = (int)kf;
  float r  = fmaf(-kf, kP1, x);
  r = fmaf(-kf, kP2, r);
  r = fmaf(-kf, kP3, r);
  r = fmaf(-kf, kP4, r);

  float z = r * r;
  float sp = fmaf(fmaf(-1.9515295891e-4f, z, 8.3321608736e-3f), z, -1.6666654611e-1f);
  float s  = fmaf(sp * z, r, r);
  float cp = fmaf(fmaf(2.443315711809948e-5f, z, -1.388731625493765e-3f), z,
                  4.166664568298827e-2f);
  float c  = fmaf(cp, z * z, fmaf(-0.5f, z, 1.0f));

  bool sw = (q & 1) != 0;
  float ss = sw ? c : s;
  float cc = sw ? s : c;
  unsigned sgn_s = (unsigned)(q & 2) << 30;
  unsigned sgn_c = (unsigned)((q + 1) & 2) << 30;
  s_out = __uint_as_float(__float_as_uint(ss) ^ sgn_s);
  c_out = __uint_as_float(__float_as_uint(cc) ^ sgn_c);
}

// Round-9 shape — the empirical optimum (39.2 us, VALUBusy 93%, VGPR 40,
// zero spill): one 256-thread block per (b,f) bin, EPT=8, per-thread arrays
// live across both passes. All alternatives counter-refuted:
//   EPT=16 @2-wave block -> occupancy 26% (R2); EPT=16 @4-wave -> spill (R10);
//   1 wave/bin EPT=32 -> starvation, VALUBusy 54% (R8);
//   packed fp32 -> pipe-neutral on gfx950 (R5);
//   sum-rotation / Delta-Taylor pass-2 -> phase razor 2*pi flip (R6/R7).
__launch_bounds__(kTPB, 4)
__global__ void wavelet_ls_kernel(const float* __restrict__ ys,
                                  const float* __restrict__ ts,
                                  const float* __restrict__ freq,
                                  float* __restrict__ out) {
  const int f    = blockIdx.x;   // frequency index
  const int b    = blockIdx.y;   // batch index
  const int tid  = threadIdx.x;
  const int wave = tid >> 6;

  const float* __restrict__ tsb = ts + b * kNTS;
  const float* __restrict__ ysb = ys + b * kNTS;
  const float4* __restrict__ ts4 = (const float4*)tsb;
  const float4* __restrict__ ys4 = (const float4*)ysb;

  const float tau   = 0.5f * (tsb[kNTS / 2] + tsb[kNTS / 2 + 1]);
  const float omega = freq[f] * kTwoPi;

  // Per-thread sample state kept across both passes.
  float tv[kEPT], wv[kEPT], wyv[kEPT];

  float acc[6];
#pragma unroll
  for (int i = 0; i < 6; ++i) acc[i] = 0.0f;

#pragma unroll
  for (int v = 0; v < kVPT; ++v) {
    const int vidx = v * kTPB + tid;      // coalesced float4
    const float4 t4 = ts4[vidx];
    const float4 y4 = ys4[vidx];
    const float te[4] = {t4.x, t4.y, t4.z, t4.w};
    const float ye[4] = {y4.x, y4.y, y4.z, y4.w};
#pragma unroll
    for (int j = 0; j < 4; ++j) {
      const int k = v * 4 + j;
      const float t = te[j];
      const float y = ye[j];
      tv[k] = t;
      const float dz = omega * (t - tau);      // ref rounding structure
      const float e2 = (-kCL2 * dz) * dz;      // exp2-domain exponent
      const float w  = __builtin_amdgcn_exp2f(e2);
      wv[k]  = w;
      wyv[k] = w * y;
      float sn, cs;
      fast_sincosf(omega * t, sn, cs);         // theta = fl(omega*t)
      const float c2 = fmaf(-2.0f * sn, sn, 1.0f);   // cos^2 - sin^2
      acc[0] += w;
      acc[1] = fmaf(w, sn, acc[1]);
      acc[2] = fmaf(w, cs, acc[2]);
      acc[3] = fmaf(w, sn * cs, acc[3]);
      acc[4] = fmaf(w, c2, acc[4]);
      acc[5] = fmaf(w, y, acc[5]);
    }
  }

  // Butterfly within wave; combine the 4 waves via LDS.
  __shared__ float lds1[4][6];
#pragma unroll
  for (int i = 0; i < 6; ++i) {
    float v = acc[i];
#pragma unroll
    for (int off = 1; off < 64; off <<= 1) v += __shfl_xor(v, off, 64);
    if ((tid & 63) == 0) lds1[wave][i] = v;
  }
  __syncthreads();

  float tot[6];
#pragma unroll
  for (int i = 0; i < 6; ++i)
    tot[i] = (lds1[0][i] + lds1[1][i]) + (lds1[2][i] + lds1[3][i]);

  const float sum_w   = tot[0];
  const float inv_w   = 1.0f / sum_w;
  const float sin_one = tot[1] * inv_w;
  const float cos_one = tot[2] * inv_w;
  const float sin_cos = tot[3] * inv_w;
  const float cc_ss   = tot[4] * inv_w;    // cos_cos - sin_sin
  const float ys_one  = tot[5] * inv_w;

  const float num = 2.0f * (sin_cos - sin_one * cos_one);
  const float den = cc_ss - cos_one * cos_one + sin_one * sin_one;
  const float time_shift = atan2f(num, den) / (2.0f * omega);

  // Pass 2: full per-element recompute of sincos(omega*(t - time_shift)).
  // (Rounds 6/7 proved any cheaper path perturbs a2 by ~1e-5 at razor bins
  //  and flips atan2 by 2*pi.)
  float a20 = 0.0f, a21 = 0.0f, a22 = 0.0f, a23 = 0.0f;
#pragma unroll
  for (int k = 0; k < kEPT; ++k) {
    float sn, cs;
    fast_sincosf(omega * (tv[k] - time_shift), sn, cs);   // ref's phase_arg
    const float w  = wv[k];
    const float wy = wyv[k];
    a20 = fmaf(w,  cs, a20);    // -> cos_shift_one
    a21 = fmaf(w,  sn, a21);    // -> sin_shift_one
    a22 = fmaf(wy, cs, a22);    // -> ys_cos_shift
    a23 = fmaf(wy, sn, a23);    // -> ys_sin_shift
  }

  __shared__ float lds2[4][4];
  {
    float av[4] = {a20, a21, a22, a23};
#pragma unroll
    for (int i = 0; i < 4; ++i) {
      float v = av[i];
#pragma unroll
      for (int off = 1; off < 64; off <<= 1) v += __shfl_xor(v, off, 64);
      if ((tid & 63) == 0) lds2[wave][i] = v;
    }
  }
  __syncthreads();

  if (tid == 0) {
    float t2[4];
#pragma unroll
    for (int i = 0; i < 4; ++i)
      t2[i] = (lds2[0][i] + lds2[1][i]) + (lds2[2][i] + lds2[3][i]);

    const float cos_shift_one = t2[0] * inv_w;
    const float sin_shift_one = t2[1] * inv_w;
    const float ys_cos_shift  = t2[2] * inv_w;
    const float ys_sin_shift  = t2[3] * inv_w;

    float stc, ctc;
    sincosf(omega * (time_shift - tau), &stc, &ctc);  // once per block: keep libm

    const float A  = 2.0f * (ys_cos_shift - ys_one * cos_shift_one);
    const float B  = 2.0f * (ys_sin_shift - ys_one * sin_shift_one);
    const float a0 = ys_one;
    const float a1 = ctc * A - stc * B;
    const float a2 = stc * A + ctc * B;
    const float wwp   = a1 * a1 + a2 * a2;
    const float phase = atan2f(a2, a1);

    const int o = b * kNF + f;
    out[0 * kNB * kNF + o] = wwp;
    out[1 * kNB * kNF + o] = phase;
    out[2 * kNB * kNF + o] = a0;
    out[3 * kNB * kNF + o] = a1;
    out[4 * kNB * kNF + o] = a2;
  }
}

extern "C" void kernel_launch(void* const* d_in, const int* in_sizes, int n_in,
                              void* d_out, int out_size, void* d_ws, size_t ws_size,
                              hipStream_t stream) {
  const float* ys   = (const float*)d_in[0];
  const float* ts   = (const float*)d_in[1];
  const float* freq = (const float*)d_in[2];
  float* out = (float*)d_out;

  dim3 grid(kNF, kNB);
  wavelet_ls_kernel<<<grid, kTPB, 0, stream>>>(ys, ts, freq, out);
}